// Round 6
// baseline (1439.750 us; speedup 1.0000x reference)
//
#include <hip/hip_runtime.h>
#include <stdint.h>

#define D 128
#define TN 160000
#define NSUB 3200
#define GG 64
#define NL 4

typedef __bf16 bf16x8 __attribute__((ext_vector_type(8)));
typedef float f32x4 __attribute__((ext_vector_type(4)));
typedef unsigned int u32x4 __attribute__((ext_vector_type(4)));

__device__ __forceinline__ unsigned short f2bf(float v) {
    union { float f; uint32_t u; } c; c.f = v;
    uint32_t r = c.u + 0x7fffu + ((c.u >> 16) & 1u);
    return (unsigned short)(r >> 16);
}
__device__ __forceinline__ float bf2f(unsigned short h) {
    union { float f; uint32_t u; } c; c.u = ((uint32_t)h) << 16;
    return c.f;
}

__device__ __forceinline__ void gload16(const void* g, void* l) {
    __builtin_amdgcn_global_load_lds(
        (const __attribute__((address_space(1))) unsigned int*)g,
        (__attribute__((address_space(3))) unsigned int*)l, 16, 0, 0);
}

// ---------------------------------------------------------------------------
// Fused GraphConv via MFMA. Block = 2 units (100 rows) x 256 cols.
// A3: [M][256] bf16 = [hi|lo] of x, staged ONCE into LDS, source-XOR-swizzled
// (granule g at row r holds global granule g^(r&7)); frag ds_reads apply the
// same XOR -> minimal bank cycles. B fragments per-lane from global (L2),
// one load per tile (k-steps paired to reuse B registers). No K-loop barriers.
// Virtual K = 384: hi*Whi + lo*Whi + hi*Wlo (12 steps of k=32).
// Epilogue: Yn -> agg LDS (overlays A), CSR aggregation -> h -> agg,
// then ALL threads stream agg -> H with coalesced 256B/wave stores, with
// BN sum/sumsq fused into the same loop -> 64-way replicated atomics.
// ---------------------------------------------------------------------------
__global__ __launch_bounds__(256, 3)
void gconv_kernel(const unsigned short* __restrict__ A3,
                  const unsigned short* __restrict__ Wt,
                  const float* __restrict__ bias,
                  const int* __restrict__ rp,
                  const unsigned char* __restrict__ colx,
                  float* __restrict__ H,
                  float* __restrict__ stats)
{
    __shared__ __align__(16) char lds[53248];
    float* agg = (float*)lds;                           // [100][130] overlay, 52000B
    int* rpl = (int*)(lds + 52000);                     // 102 ints
    unsigned char* coll = (unsigned char*)(lds + 52408);// 800B

    const int tid = threadIdx.x;
    const int blk = blockIdx.x;
    const int rowbase = blk * 100;
    const int lane = tid & 63, wv = tid >> 6;
    const int p = lane & 15, q = lane >> 4;
    const int wn0 = wv * 64;

    // ---- stage A once: 3200 granules of 16B, source-swizzled ----
#pragma unroll
    for (int i = 0; i < 12; ++i) {
        const int c = i * 256 + tid;
        const int r = c >> 5, g = c & 31;
        gload16(A3 + (size_t)(rowbase + r) * 256 + ((g ^ (r & 7)) << 3),
                lds + ((i * 256 + (wv << 6)) << 4));
    }
    if (wv < 2) {
        const int c = 3072 + (wv << 6) + lane;
        const int r = c >> 5, g = c & 31;
        gload16(A3 + (size_t)(rowbase + r) * 256 + ((g ^ (r & 7)) << 3),
                lds + ((3072 + (wv << 6)) << 4));
    }
    if (tid < 102) rpl[tid] = rp[blk * 102 + tid];
    if (tid < 200)
        ((uint32_t*)coll)[tid] = ((const uint32_t*)(colx + (size_t)blk * 800))[tid];

    f32x4 acc[7][4];
#pragma unroll
    for (int i = 0; i < 7; ++i)
#pragma unroll
        for (int j = 0; j < 4; ++j) acc[i][j] = (f32x4){0.f, 0.f, 0.f, 0.f};

    __syncthreads();

    // ---- K-loop: 12 virtual k-steps, paired so each B tile loads once ----
    static const int MROW[7] = {0, 16, 32, 48, 64, 80, 84};
    static const int BST[12] = {0, 0, 1, 1, 2, 2, 3, 3, 4, 5, 6, 7};
    static const int KAT[12] = {0, 128, 32, 160, 64, 192, 96, 224, 0, 32, 64, 96};
    bf16x8 bfr[4];
#pragma unroll
    for (int s = 0; s < 12; ++s) {
        const int bs = BST[s], ka = KAT[s];
        if (s >= 8 || (s & 1) == 0) {
#pragma unroll
            for (int ni = 0; ni < 4; ++ni) {
                const int n = wn0 + ni * 16 + p;
                u32x4 raw = *(const u32x4*)(Wt + ((size_t)bs << 13) + n * 32 + q * 8);
                bfr[ni] = __builtin_bit_cast(bf16x8, raw);
            }
        }
        const int gbase = (ka >> 3) + q;
#pragma unroll
        for (int mi = 0; mi < 7; ++mi) {
            const int r = MROW[mi] + p;
            u32x4 raw = *(const u32x4*)(lds + r * 512 + ((gbase ^ (r & 7)) << 4));
            bf16x8 afr = __builtin_bit_cast(bf16x8, raw);
#pragma unroll
            for (int ni = 0; ni < 4; ++ni)
                acc[mi][ni] = __builtin_amdgcn_mfma_f32_16x16x32_bf16(afr, bfr[ni], acc[mi][ni], 0, 0, 0);
        }
    }

    __syncthreads();   // all A-frag reads done; A region may become agg

    // waves 2,3 hold Yn (GEMM cols 128:255): dump to agg
    if (wv >= 2) {
#pragma unroll
        for (int mi = 0; mi < 7; ++mi)
#pragma unroll
            for (int r = 0; r < 4; ++r) {
                const int row = MROW[mi] + q * 4 + r;
                if (mi == 6 && row < 96) continue;
#pragma unroll
                for (int ni = 0; ni < 4; ++ni)
                    agg[row * 130 + (wn0 - 128) + ni * 16 + p] = acc[mi][ni][r];
            }
    }
    __syncthreads();

    // waves 0,1 hold Yr (cols 0:127): CSR aggregate + bias -> acc, then -> agg
    if (wv < 2) {
        float bsv[4];
#pragma unroll
        for (int ni = 0; ni < 4; ++ni) bsv[ni] = bias[wn0 + ni * 16 + p];
#pragma unroll
        for (int mi = 0; mi < 7; ++mi)
#pragma unroll
            for (int r = 0; r < 4; ++r) {
                const int row = MROW[mi] + q * 4 + r;
                if (mi == 6 && row < 96) continue;
                const int ul = row >= 50 ? 1 : 0;
                const int dl = row - ul * 50;
                const int e0 = rpl[ul * 51 + dl], e1 = rpl[ul * 51 + dl + 1];
                float s0 = 0.f, s1 = 0.f, s2 = 0.f, s3 = 0.f;
                for (int e = e0; e < e1; ++e) {
                    const int sr = (int)coll[ul * 400 + e] + ul * 50;
                    s0 += agg[sr * 130 + wn0 + p];
                    s1 += agg[sr * 130 + wn0 + 16 + p];
                    s2 += agg[sr * 130 + wn0 + 32 + p];
                    s3 += agg[sr * 130 + wn0 + 48 + p];
                }
                acc[mi][0][r] += s0 + bsv[0];
                acc[mi][1][r] += s1 + bsv[1];
                acc[mi][2][r] += s2 + bsv[2];
                acc[mi][3][r] += s3 + bsv[3];
            }
        // write h into agg (own disjoint cols; all reads of Yn done per-wave)
#pragma unroll
        for (int mi = 0; mi < 7; ++mi)
#pragma unroll
            for (int r = 0; r < 4; ++r) {
                const int row = MROW[mi] + q * 4 + r;
                if (mi == 6 && row < 96) continue;
#pragma unroll
                for (int ni = 0; ni < 4; ++ni)
                    agg[row * 130 + wn0 + ni * 16 + p] = acc[mi][ni][r];
            }
    }
    __syncthreads();

    // all 256 threads: coalesced H store (256B/wave) + fused BN stats
    {
        const int c = tid & 127;
        const int r0 = tid >> 7;       // 0 or 1
        float sm = 0.f, sq = 0.f;
#pragma unroll
        for (int i = 0; i < 50; ++i) {
            const int row = r0 + 2 * i;
            const float v = agg[row * 130 + c];
            H[(size_t)(rowbase + row) * 128 + c] = v;
            sm += v; sq += v * v;
        }
        float* rep = stats + (size_t)(blk & 63) * 256;
        atomicAdd(&rep[c], sm);
        atomicAdd(&rep[128 + c], sq);
    }
}

// ---------------------------------------------------------------------------
// fuse (BN1+BN2[node_idx]+relu) + bf16 split -> A3, and subgraph-mean -> XS.
// One block per original node (g,n): 50 subgraph-copy rows x 128 ch.
// ---------------------------------------------------------------------------
template <bool FUSE>
__global__ __launch_bounds__(256)
void fusexsum_kernel(const float* __restrict__ HP,
                     const float* __restrict__ H2,
                     const float* __restrict__ prm,
                     unsigned short* __restrict__ A3,
                     unsigned short* __restrict__ XS)
{
    __shared__ float red[256];
    const int blk = blockIdx.x;          // g*50 + n
    const int g = blk / 50, n = blk - g * 50;
    const int tid = threadIdx.x;
    const int c = tid & 127, sh = tid >> 7;
    float a1 = 0.f, c1 = 0.f, hh = 0.f;
    if (FUSE) {
        a1 = prm[c]; c1 = prm[128 + c];
        const float a2 = prm[256 + c], c2 = prm[384 + c];
        hh = a2 * H2[(size_t)blk * 128 + c] + c2;
    }
    float accum = 0.f;
    const int s0 = sh * 25;
    for (int s = s0; s < s0 + 25; ++s) {
        const size_t row = (size_t)g * 2500 + s * 50 + n;
        float v = HP[row * 128 + c];
        if (FUSE) v = fmaxf(0.f, a1 * v + c1 + hh);
        const unsigned short hi = f2bf(v);
        const unsigned short lo = f2bf(v - bf2f(hi));
        A3[row * 256 + c] = hi;
        A3[row * 256 + 128 + c] = lo;
        accum += v;
    }
    red[tid] = accum;
    __syncthreads();
    if (tid < 128) {
        const float xv = (red[tid] + red[tid + 128]) * 0.02f;
        const unsigned short hi = f2bf(xv);
        const unsigned short lo = f2bf(xv - bf2f(hi));
        XS[(size_t)blk * 256 + c] = hi;
        XS[(size_t)blk * 256 + 128 + c] = lo;
    }
}

// per-unit CSR build: 50 nodes, 400 edges, all endpoints inside the unit
__global__ void csr_build(const int* __restrict__ src, const int* __restrict__ dst,
                          int* __restrict__ rp, unsigned char* __restrict__ colx)
{
    __shared__ int cnt[50];
    __shared__ int base[51];
    __shared__ short dl[400], sl[400];
    const int u = blockIdx.x, t = threadIdx.x;   // 64 threads
    if (t < 50) cnt[t] = 0;
    __syncthreads();
    for (int e = t; e < 400; e += 64) {
        const int dd = dst[u * 400 + e] - u * 50;
        const int ss = src[u * 400 + e] - u * 50;
        dl[e] = (short)dd; sl[e] = (short)ss;
        atomicAdd(&cnt[dd], 1);
    }
    __syncthreads();
    if (t == 0) {
        int s = 0;
        for (int i = 0; i < 50; ++i) { base[i] = s; s += cnt[i]; }
        base[50] = 400;
    }
    __syncthreads();
    if (t < 51) rp[u * 51 + t] = base[t];
    if (t < 50) cnt[t] = base[t];
    __syncthreads();
    for (int e = t; e < 400; e += 64) {
        const int pos = atomicAdd(&cnt[dl[e]], 1);
        colx[u * 400 + pos] = (unsigned char)sl[e];
    }
}

// build W3T: 8 matrices x 8 tiles x [256 n][32 k] bf16; tiles 0-3 hi, 4-7 lo
__global__ void w3t_kernel(const float* __restrict__ Wr, const float* __restrict__ Wn,
                           const float* __restrict__ Wsr, const float* __restrict__ Wsn,
                           unsigned short* __restrict__ W3T)
{
    const int idx = blockIdx.x * 256 + threadIdx.x;  // 8*65536
    const int m = idx >> 16;
    const int r = idx & 65535;
    const int bt = r >> 13;
    const int rr = r & 8191;
    const int n = rr >> 5, kloc = rr & 31;
    const int kg = (bt & 3) * 32 + kloc;
    const float* Wa = (m < 4) ? Wr + (size_t)m * 16384 : Wsr + (size_t)(m - 4) * 16384;
    const float* Wb = (m < 4) ? Wn + (size_t)m * 16384 : Wsn + (size_t)(m - 4) * 16384;
    const float w = (n < 128) ? Wa[kg * 128 + n] : Wb[kg * 128 + (n - 128)];
    const unsigned short hi = f2bf(w);
    W3T[idx] = (bt < 4) ? hi : f2bf(w - bf2f(hi));
}

// finalize BN params from 64-replica stats; prm = [a1,c1,a2,c2]; re-zero reps
__global__ void bnfin_kernel(float* __restrict__ stats,
                             const float* __restrict__ bng, const float* __restrict__ bnb,
                             const float* __restrict__ bnsg, const float* __restrict__ bnsb,
                             float* __restrict__ prm)
{
    __shared__ float sN[256], sS[256];
    const int tid = threadIdx.x;
    float aN = 0.f, aS = 0.f;
    for (int r = 0; r < 64; ++r) {
        aN += stats[r * 256 + tid];
        aS += stats[16384 + r * 256 + tid];
    }
    sN[tid] = aN; sS[tid] = aS;
    __syncthreads();
    if (tid < 128) {
        const float mu = sN[tid] / (float)TN;
        const float var = sN[128 + tid] / (float)TN - mu * mu;
        const float a = bng[tid] / sqrtf(var + 1e-5f);
        prm[tid] = a;
        prm[128 + tid] = bnb[tid] - mu * a;
    } else {
        const int c = tid - 128;
        const float mu = sS[c] / (float)NSUB;
        const float var = sS[128 + c] / (float)NSUB - mu * mu;
        const float a = bnsg[c] / sqrtf(var + 1e-5f);
        prm[256 + c] = a;
        prm[384 + c] = bnsb[c] - mu * a;
    }
    for (int i = tid; i < 32768; i += 256) stats[i] = 0.f;
}

// graph pooling from XS: mean over n
__global__ void pool_kernel(const unsigned short* __restrict__ XS, float* __restrict__ hg)
{
    const int g = blockIdx.x, c = threadIdx.x;   // 128 threads
    float s = 0.f;
    for (int n = 0; n < 50; ++n) {
        const unsigned short* pp = XS + (size_t)(g * 50 + n) * 256;
        s += bf2f(pp[c]) + bf2f(pp[128 + c]);
    }
    hg[g * 128 + c] = s * 0.02f;
}

__global__ void mlp_kernel(const float* __restrict__ hg,
                           const float* __restrict__ W1, const float* __restrict__ b1,
                           const float* __restrict__ W2, const float* __restrict__ b2,
                           float* __restrict__ out)
{
    __shared__ float xv[128];
    __shared__ float hid[256];
    const int g = blockIdx.x, tid = threadIdx.x;
    if (tid < 128) xv[tid] = hg[g * 128 + tid];
    __syncthreads();
    float a = b1[tid];
    for (int k = 0; k < 128; ++k) a += xv[k] * W1[k * 256 + tid];
    hid[tid] = fmaxf(a, 0.f);
    __syncthreads();
    if (tid < 10) {
        float o = b2[tid];
        for (int k = 0; k < 256; ++k) o += hid[k] * W2[k * 10 + tid];
        out[g * 10 + tid] = o;
    }
}

__global__ void zero_kernel(float* __restrict__ pz, int n)
{
    const int t = blockIdx.x * 256 + threadIdx.x;
    if (t < n) pz[t] = 0.f;
}

extern "C" void kernel_launch(void* const* d_in, const int* in_sizes, int n_in,
                              void* d_out, int out_size, void* d_ws, size_t ws_size,
                              hipStream_t stream)
{
    const float* x0   = (const float*)d_in[0];
    const float* Wr   = (const float*)d_in[1];
    const float* Wn   = (const float*)d_in[2];
    const float* bb   = (const float*)d_in[3];
    const float* bng  = (const float*)d_in[4];
    const float* bnb  = (const float*)d_in[5];
    const float* Wsr  = (const float*)d_in[6];
    const float* Wsn  = (const float*)d_in[7];
    const float* bs   = (const float*)d_in[8];
    const float* bnsg = (const float*)d_in[9];
    const float* bnsb = (const float*)d_in[10];
    const float* fW1  = (const float*)d_in[11];
    const float* fb1  = (const float*)d_in[12];
    const float* fW2  = (const float*)d_in[13];
    const float* fb2  = (const float*)d_in[14];
    const int* ei     = (const int*)d_in[15];
    const int* oei    = (const int*)d_in[16];
    float* out        = (float*)d_out;

    char* w = (char*)d_ws;
    unsigned short* A3  = (unsigned short*)w; w += (size_t)TN * 256 * 2;
    float* H1           = (float*)w;          w += (size_t)TN * 128 * 4;
    unsigned short* W3T = (unsigned short*)w; w += (size_t)8 * 65536 * 2;
    unsigned short* XS  = (unsigned short*)w; w += (size_t)NSUB * 256 * 2;
    float* H2           = (float*)w;          w += (size_t)NSUB * 128 * 4;
    int* rps            = (int*)w;            w += (size_t)NSUB * 51 * 4;
    unsigned char* cls  = (unsigned char*)w;  w += (size_t)NSUB * 400;
    int* rpo            = (int*)w;            w += (size_t)GG * 51 * 4;
    unsigned char* clo  = (unsigned char*)w;  w += (size_t)GG * 400;
    float* stats        = (float*)w;          w += (size_t)32768 * 4;  // [2][64][256]
    float* prm          = (float*)w;          w += 512 * 4;
    float* hg           = (float*)w;          w += (size_t)GG * 128 * 4;

    w3t_kernel<<<2048, 256, 0, stream>>>(Wr, Wn, Wsr, Wsn, W3T);
    csr_build<<<NSUB, 64, 0, stream>>>(ei, ei + 1280000, rps, cls);
    csr_build<<<GG, 64, 0, stream>>>(oei, oei + 25600, rpo, clo);
    zero_kernel<<<128, 256, 0, stream>>>(stats, 32768);
    fusexsum_kernel<false><<<NSUB, 256, 0, stream>>>(x0, nullptr, nullptr, A3, XS);

    for (int i = 0; i < NL; ++i) {
        gconv_kernel<<<TN / 100, 256, 0, stream>>>(A3, W3T + (size_t)i * 65536,
                                                   bb + i * 128, rps, cls, H1, stats);
        gconv_kernel<<<NSUB / 100, 256, 0, stream>>>(XS, W3T + (size_t)(4 + i) * 65536,
                                                     bs + i * 128, rpo, clo, H2, stats + 16384);
        bnfin_kernel<<<1, 256, 0, stream>>>(stats, bng + i * 128, bnb + i * 128,
                                            bnsg + i * 128, bnsb + i * 128, prm);
        fusexsum_kernel<true><<<NSUB, 256, 0, stream>>>(H1, H2, prm, A3, XS);
    }

    pool_kernel<<<GG, 128, 0, stream>>>(XS, hg);
    mlp_kernel<<<GG, 256, 0, stream>>>(hg, fW1, fb1, fW2, fb2, out);
}

// Round 7
// 944.319 us; speedup vs baseline: 1.5246x; 1.5246x over previous
//
#include <hip/hip_runtime.h>
#include <stdint.h>

#define D 128
#define TN 160000
#define NSUB 3200
#define GG 64
#define NL 4

typedef __bf16 bf16x8 __attribute__((ext_vector_type(8)));
typedef float f32x4 __attribute__((ext_vector_type(4)));
typedef unsigned int u32x4 __attribute__((ext_vector_type(4)));

__device__ __forceinline__ unsigned short f2bf(float v) {
    union { float f; uint32_t u; } c; c.f = v;
    uint32_t r = c.u + 0x7fffu + ((c.u >> 16) & 1u);
    return (unsigned short)(r >> 16);
}
__device__ __forceinline__ float bf2f(unsigned short h) {
    union { float f; uint32_t u; } c; c.u = ((uint32_t)h) << 16;
    return c.f;
}

__device__ __forceinline__ void gload16(const void* g, void* l) {
    __builtin_amdgcn_global_load_lds(
        (const __attribute__((address_space(1))) unsigned int*)g,
        (__attribute__((address_space(3))) unsigned int*)l, 16, 0, 0);
}

// ---------------------------------------------------------------------------
// Fused GraphConv via MFMA. Block = 2 units (100 rows) x 256 cols.
// A3: [M][256] bf16 = [hi|lo] of x, staged ONCE into LDS (source-XOR-swizzled,
// frag reads apply the same XOR). B staged tile-by-tile (16KB) via
// global_load_lds into LDS: fragments are read to REGISTERS first, then the
// single buffer is re-staged with tile t+1 while tile t's MFMAs run.
// 17 barriers total (vs 24 in the r3 structure).
// Virtual K = 384: hi*Whi + lo*Whi + hi*Wlo; tiles 0-3 = Whi (2 A-substeps),
// 4-7 = Wlo (1 A-substep). M=100 via m-frags {0,16,32,48,64,80,84} with
// duplicate rows 84..95 of frag 6 skipped at write.
// Epilogue: Yn -> agg LDS (overlays A+B), CSR aggregation, H scattered
// stores (r3 form, clean counters); BN stats -> 64-way replicated atomics.
// ---------------------------------------------------------------------------
__global__ __launch_bounds__(256, 2)
void gconv_kernel(const unsigned short* __restrict__ A3,
                  const unsigned short* __restrict__ Wt,
                  const float* __restrict__ bias,
                  const int* __restrict__ rp,
                  const unsigned char* __restrict__ colx,
                  float* __restrict__ H,
                  float* __restrict__ stats)
{
    __shared__ __align__(16) char lds[68800];
    unsigned short* Blds = (unsigned short*)(lds + 51200);  // [256n][32k], 16KB
    float* agg = (float*)lds;                               // [100][130] overlay
    int* rpl = (int*)(lds + 67584);                         // 102 ints
    unsigned char* coll = (unsigned char*)(lds + 67992);    // 800B

    const int tid = threadIdx.x;
    const int blk = blockIdx.x;
    const int rowbase = blk * 100;
    const int lane = tid & 63, wv = tid >> 6;
    const int p = lane & 15, q = lane >> 4;
    const int wn0 = wv * 64;

    // ---- stage A once: 3200 granules of 16B, source-swizzled ----
#pragma unroll
    for (int i = 0; i < 12; ++i) {
        const int c = i * 256 + tid;
        const int r = c >> 5, g = c & 31;
        gload16(A3 + (size_t)(rowbase + r) * 256 + ((g ^ (r & 7)) << 3),
                lds + ((i * 256 + (wv << 6)) << 4));
    }
    if (wv < 2) {
        const int c = 3072 + (wv << 6) + lane;
        const int r = c >> 5, g = c & 31;
        gload16(A3 + (size_t)(rowbase + r) * 256 + ((g ^ (r & 7)) << 3),
                lds + ((3072 + (wv << 6)) << 4));
    }
    // ---- stage B tile 0 ----
#pragma unroll
    for (int rr = 0; rr < 4; ++rr) {
        const int cb = rr * 256 + (wv << 6);
        gload16(Wt + (size_t)(cb + lane) * 8, Blds + cb * 8);
    }
    if (tid < 102) rpl[tid] = rp[blk * 102 + tid];
    if (tid < 200)
        ((uint32_t*)coll)[tid] = ((const uint32_t*)(colx + (size_t)blk * 800))[tid];

    f32x4 acc[7][4];
#pragma unroll
    for (int i = 0; i < 7; ++i)
#pragma unroll
        for (int j = 0; j < 4; ++j) acc[i][j] = (f32x4){0.f, 0.f, 0.f, 0.f};

    __syncthreads();   // barrier 1: A + B0 + metadata ready

    // ---- K-loop: 8 B-tiles, frags->regs then re-stage the single buffer ----
    static const int MROW[7] = {0, 16, 32, 48, 64, 80, 84};
    bf16x8 bfr[4];
#pragma unroll
    for (int t = 0; t < 8; ++t) {
        // read this tile's B fragments into registers
#pragma unroll
        for (int ni = 0; ni < 4; ++ni) {
            u32x4 raw = *(const u32x4*)&Blds[(wn0 + ni * 16 + p) * 32 + q * 8];
            bfr[ni] = __builtin_bit_cast(bf16x8, raw);
        }
        __syncthreads();               // all waves hold frags; buffer reusable
        if (t < 7) {
#pragma unroll
            for (int rr = 0; rr < 4; ++rr) {
                const int cb = rr * 256 + (wv << 6);
                gload16(Wt + ((size_t)(t + 1) << 13) + (size_t)(cb + lane) * 8,
                        Blds + cb * 8);
            }
        }
        const int na = (t < 4) ? 2 : 1;
        for (int a = 0; a < na; ++a) {
            const int ka = (t < 4) ? (t * 32 + a * 128) : ((t - 4) * 32);
            const int gbase = (ka >> 3) + q;
#pragma unroll
            for (int mi = 0; mi < 7; ++mi) {
                const int r = MROW[mi] + p;
                u32x4 raw = *(const u32x4*)(lds + r * 512 + ((gbase ^ (r & 7)) << 4));
                bf16x8 afr = __builtin_bit_cast(bf16x8, raw);
#pragma unroll
                for (int ni = 0; ni < 4; ++ni)
                    acc[mi][ni] = __builtin_amdgcn_mfma_f32_16x16x32_bf16(afr, bfr[ni], acc[mi][ni], 0, 0, 0);
            }
        }
        __syncthreads();               // stage t+1 drained; compute done
    }

    // ---- epilogue (r5-verified form, scattered H stores) ----
    // waves 2,3 hold Yn (GEMM cols 128:255): dump to agg
    if (wv >= 2) {
#pragma unroll
        for (int mi = 0; mi < 7; ++mi)
#pragma unroll
            for (int r = 0; r < 4; ++r) {
                const int row = MROW[mi] + q * 4 + r;
                if (mi == 6 && row < 96) continue;
#pragma unroll
                for (int ni = 0; ni < 4; ++ni)
                    agg[row * 130 + (wn0 - 128) + ni * 16 + p] = acc[mi][ni][r];
            }
    }
    __syncthreads();

    // waves 0,1 hold Yr (cols 0:127): CSR aggregate + bias, write H
    if (wv < 2) {
        float bsv[4];
#pragma unroll
        for (int ni = 0; ni < 4; ++ni) bsv[ni] = bias[wn0 + ni * 16 + p];
#pragma unroll
        for (int mi = 0; mi < 7; ++mi)
#pragma unroll
            for (int r = 0; r < 4; ++r) {
                const int row = MROW[mi] + q * 4 + r;
                if (mi == 6 && row < 96) continue;
                const int ul = row >= 50 ? 1 : 0;
                const int dl = row - ul * 50;
                const int e0 = rpl[ul * 51 + dl], e1 = rpl[ul * 51 + dl + 1];
                float s0 = 0.f, s1 = 0.f, s2 = 0.f, s3 = 0.f;
                for (int e = e0; e < e1; ++e) {
                    const int sr = (int)coll[ul * 400 + e] + ul * 50;
                    s0 += agg[sr * 130 + wn0 + p];
                    s1 += agg[sr * 130 + wn0 + 16 + p];
                    s2 += agg[sr * 130 + wn0 + 32 + p];
                    s3 += agg[sr * 130 + wn0 + 48 + p];
                }
#pragma unroll
                for (int ni = 0; ni < 4; ++ni) {
                    const float sv = (ni == 0) ? s0 : (ni == 1) ? s1 : (ni == 2) ? s2 : s3;
                    const int cc = wn0 + ni * 16 + p;
                    const float h = acc[mi][ni][r] + sv + bsv[ni];
                    acc[mi][ni][r] = h;
                    H[(size_t)(rowbase + row) * 128 + cc] = h;
                }
            }
    }
    __syncthreads();
    // waves 0,1 overwrite agg (own disjoint cols) with H for the stat reduce
    if (wv < 2) {
#pragma unroll
        for (int mi = 0; mi < 7; ++mi)
#pragma unroll
            for (int r = 0; r < 4; ++r) {
                const int row = MROW[mi] + q * 4 + r;
                if (mi == 6 && row < 96) continue;
#pragma unroll
                for (int ni = 0; ni < 4; ++ni)
                    agg[row * 130 + wn0 + ni * 16 + p] = acc[mi][ni][r];
            }
    }
    __syncthreads();
    // all 256 threads: stats partials -> replica (blk & 63)
    {
        const int c = tid & 127;
        const int r0 = (tid >> 7) * 50;
        float sm = 0.f, sq = 0.f;
        for (int r = r0; r < r0 + 50; ++r) {
            const float v = agg[r * 130 + c];
            sm += v; sq += v * v;
        }
        float* rep = stats + (size_t)(blk & 63) * 256;
        atomicAdd(&rep[c], sm);
        atomicAdd(&rep[128 + c], sq);
    }
}

// ---------------------------------------------------------------------------
// fuse (BN1+BN2[node_idx]+relu) + bf16 split -> A3, and subgraph-mean -> XS.
// One block per original node (g,n): 50 subgraph-copy rows x 128 ch.
// ---------------------------------------------------------------------------
template <bool FUSE>
__global__ __launch_bounds__(256)
void fusexsum_kernel(const float* __restrict__ HP,
                     const float* __restrict__ H2,
                     const float* __restrict__ prm,
                     unsigned short* __restrict__ A3,
                     unsigned short* __restrict__ XS)
{
    __shared__ float red[256];
    const int blk = blockIdx.x;          // g*50 + n
    const int g = blk / 50, n = blk - g * 50;
    const int tid = threadIdx.x;
    const int c = tid & 127, sh = tid >> 7;
    float a1 = 0.f, c1 = 0.f, hh = 0.f;
    if (FUSE) {
        a1 = prm[c]; c1 = prm[128 + c];
        const float a2 = prm[256 + c], c2 = prm[384 + c];
        hh = a2 * H2[(size_t)blk * 128 + c] + c2;
    }
    float accum = 0.f;
    const int s0 = sh * 25;
    for (int s = s0; s < s0 + 25; ++s) {
        const size_t row = (size_t)g * 2500 + s * 50 + n;
        float v = HP[row * 128 + c];
        if (FUSE) v = fmaxf(0.f, a1 * v + c1 + hh);
        const unsigned short hi = f2bf(v);
        const unsigned short lo = f2bf(v - bf2f(hi));
        A3[row * 256 + c] = hi;
        A3[row * 256 + 128 + c] = lo;
        accum += v;
    }
    red[tid] = accum;
    __syncthreads();
    if (tid < 128) {
        const float xv = (red[tid] + red[tid + 128]) * 0.02f;
        const unsigned short hi = f2bf(xv);
        const unsigned short lo = f2bf(xv - bf2f(hi));
        XS[(size_t)blk * 256 + c] = hi;
        XS[(size_t)blk * 256 + 128 + c] = lo;
    }
}

// per-unit CSR build: 50 nodes, 400 edges, all endpoints inside the unit
__global__ void csr_build(const int* __restrict__ src, const int* __restrict__ dst,
                          int* __restrict__ rp, unsigned char* __restrict__ colx)
{
    __shared__ int cnt[50];
    __shared__ int base[51];
    __shared__ short dl[400], sl[400];
    const int u = blockIdx.x, t = threadIdx.x;   // 64 threads
    if (t < 50) cnt[t] = 0;
    __syncthreads();
    for (int e = t; e < 400; e += 64) {
        const int dd = dst[u * 400 + e] - u * 50;
        const int ss = src[u * 400 + e] - u * 50;
        dl[e] = (short)dd; sl[e] = (short)ss;
        atomicAdd(&cnt[dd], 1);
    }
    __syncthreads();
    if (t == 0) {
        int s = 0;
        for (int i = 0; i < 50; ++i) { base[i] = s; s += cnt[i]; }
        base[50] = 400;
    }
    __syncthreads();
    if (t < 51) rp[u * 51 + t] = base[t];
    if (t < 50) cnt[t] = base[t];
    __syncthreads();
    for (int e = t; e < 400; e += 64) {
        const int pos = atomicAdd(&cnt[dl[e]], 1);
        colx[u * 400 + pos] = (unsigned char)sl[e];
    }
}

// build W3T: 8 matrices x 8 tiles x [256 n][32 k] bf16; tiles 0-3 hi, 4-7 lo
__global__ void w3t_kernel(const float* __restrict__ Wr, const float* __restrict__ Wn,
                           const float* __restrict__ Wsr, const float* __restrict__ Wsn,
                           unsigned short* __restrict__ W3T)
{
    const int idx = blockIdx.x * 256 + threadIdx.x;  // 8*65536
    const int m = idx >> 16;
    const int r = idx & 65535;
    const int bt = r >> 13;
    const int rr = r & 8191;
    const int n = rr >> 5, kloc = rr & 31;
    const int kg = (bt & 3) * 32 + kloc;
    const float* Wa = (m < 4) ? Wr + (size_t)m * 16384 : Wsr + (size_t)(m - 4) * 16384;
    const float* Wb = (m < 4) ? Wn + (size_t)m * 16384 : Wsn + (size_t)(m - 4) * 16384;
    const float w = (n < 128) ? Wa[kg * 128 + n] : Wb[kg * 128 + (n - 128)];
    const unsigned short hi = f2bf(w);
    W3T[idx] = (bt < 4) ? hi : f2bf(w - bf2f(hi));
}

// finalize BN params from 64-replica stats; prm = [a1,c1,a2,c2]; re-zero reps
__global__ void bnfin_kernel(float* __restrict__ stats,
                             const float* __restrict__ bng, const float* __restrict__ bnb,
                             const float* __restrict__ bnsg, const float* __restrict__ bnsb,
                             float* __restrict__ prm)
{
    __shared__ float sN[256], sS[256];
    const int tid = threadIdx.x;
    float aN = 0.f, aS = 0.f;
    for (int r = 0; r < 64; ++r) {
        aN += stats[r * 256 + tid];
        aS += stats[16384 + r * 256 + tid];
    }
    sN[tid] = aN; sS[tid] = aS;
    __syncthreads();
    if (tid < 128) {
        const float mu = sN[tid] / (float)TN;
        const float var = sN[128 + tid] / (float)TN - mu * mu;
        const float a = bng[tid] / sqrtf(var + 1e-5f);
        prm[tid] = a;
        prm[128 + tid] = bnb[tid] - mu * a;
    } else {
        const int c = tid - 128;
        const float mu = sS[c] / (float)NSUB;
        const float var = sS[128 + c] / (float)NSUB - mu * mu;
        const float a = bnsg[c] / sqrtf(var + 1e-5f);
        prm[256 + c] = a;
        prm[384 + c] = bnsb[c] - mu * a;
    }
    for (int i = tid; i < 32768; i += 256) stats[i] = 0.f;
}

// graph pooling from XS: mean over n
__global__ void pool_kernel(const unsigned short* __restrict__ XS, float* __restrict__ hg)
{
    const int g = blockIdx.x, c = threadIdx.x;   // 128 threads
    float s = 0.f;
    for (int n = 0; n < 50; ++n) {
        const unsigned short* pp = XS + (size_t)(g * 50 + n) * 256;
        s += bf2f(pp[c]) + bf2f(pp[128 + c]);
    }
    hg[g * 128 + c] = s * 0.02f;
}

__global__ void mlp_kernel(const float* __restrict__ hg,
                           const float* __restrict__ W1, const float* __restrict__ b1,
                           const float* __restrict__ W2, const float* __restrict__ b2,
                           float* __restrict__ out)
{
    __shared__ float xv[128];
    __shared__ float hid[256];
    const int g = blockIdx.x, tid = threadIdx.x;
    if (tid < 128) xv[tid] = hg[g * 128 + tid];
    __syncthreads();
    float a = b1[tid];
    for (int k = 0; k < 128; ++k) a += xv[k] * W1[k * 256 + tid];
    hid[tid] = fmaxf(a, 0.f);
    __syncthreads();
    if (tid < 10) {
        float o = b2[tid];
        for (int k = 0; k < 256; ++k) o += hid[k] * W2[k * 10 + tid];
        out[g * 10 + tid] = o;
    }
}

__global__ void zero_kernel(float* __restrict__ pz, int n)
{
    const int t = blockIdx.x * 256 + threadIdx.x;
    if (t < n) pz[t] = 0.f;
}

extern "C" void kernel_launch(void* const* d_in, const int* in_sizes, int n_in,
                              void* d_out, int out_size, void* d_ws, size_t ws_size,
                              hipStream_t stream)
{
    const float* x0   = (const float*)d_in[0];
    const float* Wr   = (const float*)d_in[1];
    const float* Wn   = (const float*)d_in[2];
    const float* bb   = (const float*)d_in[3];
    const float* bng  = (const float*)d_in[4];
    const float* bnb  = (const float*)d_in[5];
    const float* Wsr  = (const float*)d_in[6];
    const float* Wsn  = (const float*)d_in[7];
    const float* bs   = (const float*)d_in[8];
    const float* bnsg = (const float*)d_in[9];
    const float* bnsb = (const float*)d_in[10];
    const float* fW1  = (const float*)d_in[11];
    const float* fb1  = (const float*)d_in[12];
    const float* fW2  = (const float*)d_in[13];
    const float* fb2  = (const float*)d_in[14];
    const int* ei     = (const int*)d_in[15];
    const int* oei    = (const int*)d_in[16];
    float* out        = (float*)d_out;

    char* w = (char*)d_ws;
    unsigned short* A3  = (unsigned short*)w; w += (size_t)TN * 256 * 2;
    float* H1           = (float*)w;          w += (size_t)TN * 128 * 4;
    unsigned short* W3T = (unsigned short*)w; w += (size_t)8 * 65536 * 2;
    unsigned short* XS  = (unsigned short*)w; w += (size_t)NSUB * 256 * 2;
    float* H2           = (float*)w;          w += (size_t)NSUB * 128 * 4;
    int* rps            = (int*)w;            w += (size_t)NSUB * 51 * 4;
    unsigned char* cls  = (unsigned char*)w;  w += (size_t)NSUB * 400;
    int* rpo            = (int*)w;            w += (size_t)GG * 51 * 4;
    unsigned char* clo  = (unsigned char*)w;  w += (size_t)GG * 400;
    float* stats        = (float*)w;          w += (size_t)32768 * 4;  // [2][64][256]
    float* prm          = (float*)w;          w += 512 * 4;
    float* hg           = (float*)w;          w += (size_t)GG * 128 * 4;

    w3t_kernel<<<2048, 256, 0, stream>>>(Wr, Wn, Wsr, Wsn, W3T);
    csr_build<<<NSUB, 64, 0, stream>>>(ei, ei + 1280000, rps, cls);
    csr_build<<<GG, 64, 0, stream>>>(oei, oei + 25600, rpo, clo);
    zero_kernel<<<128, 256, 0, stream>>>(stats, 32768);
    fusexsum_kernel<false><<<NSUB, 256, 0, stream>>>(x0, nullptr, nullptr, A3, XS);

    for (int i = 0; i < NL; ++i) {
        gconv_kernel<<<TN / 100, 256, 0, stream>>>(A3, W3T + (size_t)i * 65536,
                                                   bb + i * 128, rps, cls, H1, stats);
        gconv_kernel<<<NSUB / 100, 256, 0, stream>>>(XS, W3T + (size_t)(4 + i) * 65536,
                                                     bs + i * 128, rpo, clo, H2, stats + 16384);
        bnfin_kernel<<<1, 256, 0, stream>>>(stats, bng + i * 128, bnb + i * 128,
                                            bnsg + i * 128, bnsb + i * 128, prm);
        fusexsum_kernel<true><<<NSUB, 256, 0, stream>>>(H1, H2, prm, A3, XS);
    }

    pool_kernel<<<GG, 128, 0, stream>>>(XS, hg);
    mlp_kernel<<<GG, 256, 0, stream>>>(hg, fW1, fb1, fW2, fb2, out);
}